// Round 5
// baseline (473.255 us; speedup 1.0000x reference)
//
#include <hip/hip_runtime.h>

#define N_NODES 10000
#define N_EDGESN 160000
#define E_TOT   (N_EDGESN + N_NODES)   // 170000
#define C 128
#define H 8
#define G 16
#define LLAYERS 5
#define NUM_FEAT 14
#define DIM_OUT 16
#define CH 16   // C/H
#define CG 8    // C/G
#define XSTRIDE (6*C)        // x_all row stride (6 layer slots)

// ---- counts = 1 (self loop) ----
__global__ void k_zero(int* __restrict__ counts) {
    int i = blockIdx.x * blockDim.x + threadIdx.x;
    if (i < N_NODES) counts[i] = 1;
}

// ---- degree count over original edges (by col) ----
__global__ void k_count(const int* __restrict__ col, int* __restrict__ counts) {
    int e = blockIdx.x * blockDim.x + threadIdx.x;
    if (e < N_EDGESN) atomicAdd(&counts[col[e]], 1);
}

// ---- single-block scan: counts -> exclusive offsets + cursor; dis = rsqrt(counts) ----
__global__ __launch_bounds__(1024) void k_scan(const int* __restrict__ counts,
                                               int* __restrict__ offs, int* __restrict__ cursor,
                                               float* __restrict__ dis) {
    __shared__ int part[1024];
    const int CHK = (N_NODES + 1023) / 1024;   // 10
    int t = threadIdx.x;
    int base = t * CHK;
    int loc[CHK];
    int sum = 0;
#pragma unroll
    for (int i = 0; i < CHK; i++) {
        int idx = base + i;
        int v = (idx < N_NODES) ? counts[idx] : 0;
        loc[i] = sum;
        sum += v;
    }
    part[t] = sum;
    __syncthreads();
    for (int off = 1; off < 1024; off <<= 1) {
        int v = (t >= off) ? part[t - off] : 0;
        __syncthreads();
        part[t] += v;
        __syncthreads();
    }
    int prev = (t > 0) ? part[t - 1] : 0;
#pragma unroll
    for (int i = 0; i < CHK; i++) {
        int idx = base + i;
        if (idx < N_NODES) {
            int o = prev + loc[i];
            offs[idx] = o;
            cursor[idx] = o;
            dis[idx] = rsqrtf((float)counts[idx]);
        }
    }
    if (t == 1023) offs[N_NODES] = part[1023];
}

// ---- scatter edges into dest-sorted CSR; payload = {src, dis[src]} ----
__global__ void k_scatter(const int* __restrict__ row, const int* __restrict__ col,
                          const float* __restrict__ dis,
                          int* __restrict__ cursor, int2* __restrict__ csr) {
    int e = blockIdx.x * blockDim.x + threadIdx.x;
    if (e >= E_TOT) return;
    int r = (e < N_EDGESN) ? row[e] : (e - N_EDGESN);
    int c = (e < N_EDGESN) ? col[e] : (e - N_EDGESN);
    int pos = atomicAdd(&cursor[c], 1);
    int2 pay;
    pay.x = r;
    pay.y = __float_as_int(dis[r]);
    csr[pos] = pay;
}

// ---- lin1: x (n,14) @ w (14,128) + b, relu -> x_all[:,0,:] ----
__global__ __launch_bounds__(256) void k_lin1(const float* __restrict__ x,
                                              const float* __restrict__ w,
                                              const float* __restrict__ b,
                                              float* __restrict__ x_all) {
    __shared__ float sw[NUM_FEAT * C];
    __shared__ float sb[C];
    int tid = threadIdx.x;
    for (int i = tid; i < NUM_FEAT * C; i += 256) sw[i] = w[i];
    if (tid < C) sb[tid] = b[tid];
    __syncthreads();
    int node = blockIdx.x * 2 + tid / C;
    int c = tid & (C - 1);
    if (node >= N_NODES) return;
    const float* xr = x + node * NUM_FEAT;
    float acc = sb[c];
#pragma unroll
    for (int f = 0; f < NUM_FEAT; f++) acc += xr[f] * sw[f * C + c];
    x_all[node * XSTRIDE + c] = fmaxf(acc, 0.0f);
}

__device__ __forceinline__ float dot8(const float4& a, const float4& b, const float (&w)[8]) {
    return a.x * w[0] + a.y * w[1] + a.z * w[2] + a.w * w[3]
         + b.x * w[4] + b.y * w[5] + b.z * w[6] + b.w * w[7];
}

// ---- fused attention layer: one WAVE per destination node ----
// Lane owns output channels c0=2*lane, c0+1. Each lane loads its group's full
// 8 input channels directly (2x float4, L1-shared within 4-lane group) -> no
// assembly shuffles. Explicit 2-deep edge pipeline (ping-pong A/B buffers).
template <int NL>
__global__ __launch_bounds__(256) void k_attn_fly(const int* __restrict__ offs,
                                                  const int2* __restrict__ csr,
                                                  const float* __restrict__ dis,
                                                  const float* __restrict__ Wq, const float* __restrict__ bq,
                                                  const float* __restrict__ Wk, const float* __restrict__ bk,
                                                  const float* __restrict__ Wv, const float* __restrict__ bv,
                                                  float* __restrict__ x_all) {
    const int l = NL - 1;
    int w = threadIdx.x >> 6;
    int lane = threadIdx.x & 63;
    int d = blockIdx.x * 4 + w;
    if (d >= N_NODES) return;
    int g = lane >> 2;       // channel group 0..15
    int j4 = lane & 3;
    int o0 = 2 * j4;         // output col within group
    int c0 = lane * 2;       // absolute channel

    const float* Wk_g = Wk + l * (G * CG * CG) + g * (CG * CG);
    const float* Wv_g = Wv + l * (G * CG * CG) + g * (CG * CG);
    float wkA[8], wkB[8], wvA[8], wvB[8];
#pragma unroll
    for (int i = 0; i < 8; i++) {
        wkA[i] = Wk_g[i * CG + o0];
        wkB[i] = Wk_g[i * CG + o0 + 1];
        wvA[i] = Wv_g[i * CG + o0];
        wvB[i] = Wv_g[i * CG + o0 + 1];
    }
    const float bk0 = bk[l * C + c0], bk1 = bk[l * C + c0 + 1];
    const float bv0 = bv[l * C + c0], bv1 = bv[l * C + c0 + 1];

    // q for this node from x_all[d][l]
    float qx, qy;
    {
        const float* Wq_g = Wq + l * (G * CG * CG) + g * (CG * CG);
        float wq0[8], wq1[8];
#pragma unroll
        for (int i = 0; i < 8; i++) {
            wq0[i] = Wq_g[i * CG + o0];
            wq1[i] = Wq_g[i * CG + o0 + 1];
        }
        const float* xq = x_all + (size_t)d * XSTRIDE + l * C + 8 * g;
        float4 qa = *(const float4*)(xq);
        float4 qb = *(const float4*)(xq + 4);
        qx = bq[l * C + c0] + dot8(qa, qb, wq0);
        qy = bq[l * C + c0 + 1] + dot8(qa, qb, wq1);
    }

    const float disd = dis[d];
    const int p0 = offs[d], p1 = offs[d + 1];
    const int n = p1 - p0;       // >= 1 (self loop)
    float ox = 0.0f, oy = 0.0f;
    const float scale = 0.25f;   // 1/sqrt(CH=16)

    auto loadx = [&](int s, float4 (&xa)[NL], float4 (&xb)[NL]) {
        const float* xs = x_all + (size_t)s * XSTRIDE + 8 * g;
#pragma unroll
        for (int t = 0; t < NL; t++) {
            xa[t] = *(const float4*)(xs + t * C);
            xb[t] = *(const float4*)(xs + t * C + 4);
        }
    };
    auto edge_do = [&](int2 pay, const float4 (&xa)[NL], const float4 (&xb)[NL]) {
        float nrm = disd * __int_as_float(pay.y);
        float sc[NL], vx[NL], vy[NL];
#pragma unroll
        for (int t = 0; t < NL; t++) {
            float k0 = bk0 + dot8(xa[t], xb[t], wkA);
            float k1 = bk1 + dot8(xa[t], xb[t], wkB);
            vx[t] = bv0 + dot8(xa[t], xb[t], wvA);
            vy[t] = bv1 + dot8(xa[t], xb[t], wvB);
            float pr = qx * k0 + qy * k1;
            pr += __shfl_xor(pr, 1);
            pr += __shfl_xor(pr, 2);
            pr += __shfl_xor(pr, 4);   // 8 lanes = one 16-ch head
            sc[t] = pr * scale;
        }
        float mx = sc[0];
#pragma unroll
        for (int t = 1; t < NL; t++) mx = fmaxf(mx, sc[t]);
        float sum = 0.0f;
#pragma unroll
        for (int t = 0; t < NL; t++) { sc[t] = __expf(sc[t] - mx); sum += sc[t]; }
        float inv = nrm * __builtin_amdgcn_rcpf(sum);
        float ax = 0.0f, ay = 0.0f;
#pragma unroll
        for (int t = 0; t < NL; t++) { ax += sc[t] * vx[t]; ay += sc[t] * vy[t]; }
        ox += ax * inv;
        oy += ay * inv;
    };

    float4 xaA[NL], xbA[NL], xaB[NL], xbB[NL];
    int2 payA, payB;
    payA = csr[p0];
    loadx(payA.x, xaA, xbA);
    int i = 0;
    while (i + 2 <= n) {
        payB = csr[p0 + i + 1];
        loadx(payB.x, xaB, xbB);        // B loads in flight during A compute
        edge_do(payA, xaA, xbA);
        if (i + 2 < n) {
            payA = csr[p0 + i + 2];
            loadx(payA.x, xaA, xbA);    // A loads in flight during B compute
        }
        edge_do(payB, xaB, xbB);
        i += 2;
    }
    if (i < n) edge_do(payA, xaA, xbA);

    float* dst = x_all + (size_t)d * XSTRIDE + (l + 1) * C + c0;
    dst[0] = fmaxf(ox, 0.0f);
    dst[1] = fmaxf(oy, 0.0f);
}

// ---- lin2: x_all[:,5,:] (n,128) @ w (128,16) + b -> out ----
__global__ __launch_bounds__(256) void k_lin2(const float* __restrict__ x_all,
                                              const float* __restrict__ w,
                                              const float* __restrict__ b,
                                              float* __restrict__ out) {
    __shared__ float sw[C * DIM_OUT];
    __shared__ float sb[DIM_OUT];
    __shared__ float sx[16][C];
    int tid = threadIdx.x;
    for (int i = tid; i < C * DIM_OUT; i += 256) sw[i] = w[i];
    if (tid < DIM_OUT) sb[tid] = b[tid];
    int node0 = blockIdx.x * 16;
    for (int i = tid; i < 16 * C; i += 256) {
        int nn = node0 + i / C;
        sx[i / C][i & (C - 1)] = (nn < N_NODES) ? x_all[(size_t)nn * XSTRIDE + 5 * C + (i & (C - 1))] : 0.0f;
    }
    __syncthreads();
    int node = node0 + tid / DIM_OUT;
    int o = tid & (DIM_OUT - 1);
    if (node >= N_NODES) return;
    float acc = sb[o];
    const float* xr = sx[tid / DIM_OUT];
#pragma unroll 8
    for (int c = 0; c < C; c++) acc += xr[c] * sw[c * DIM_OUT + o];
    out[node * DIM_OUT + o] = acc;
}

extern "C" void kernel_launch(void* const* d_in, const int* in_sizes, int n_in,
                              void* d_out, int out_size, void* d_ws, size_t ws_size,
                              hipStream_t stream) {
    const float* x      = (const float*)d_in[0];
    const int*   edge   = (const int*)d_in[1];
    const int*   row    = edge;              // edge_index[0]
    const int*   col    = edge + N_EDGESN;   // edge_index[1]
    const float* lin1_w = (const float*)d_in[2];
    const float* lin1_b = (const float*)d_in[3];
    const float* Wq     = (const float*)d_in[4];
    const float* bq     = (const float*)d_in[5];
    const float* Wk     = (const float*)d_in[6];
    const float* bk     = (const float*)d_in[7];
    const float* Wv     = (const float*)d_in[8];
    const float* bv     = (const float*)d_in[9];
    const float* lin2_w = (const float*)d_in[10];
    const float* lin2_b = (const float*)d_in[11];
    float* outp = (float*)d_out;

    float* ws    = (float*)d_ws;
    float* x_all = ws;                                      // n*6*C
    float* dis   = x_all + (size_t)N_NODES * XSTRIDE;       // n
    int*   counts = (int*)(dis + N_NODES);                  // n
    int*   offs   = counts + N_NODES;                       // n+1
    int*   cursor = offs + N_NODES + 1;                     // n
    int2*  csr    = (int2*)(cursor + N_NODES);              // E_TOT int2

    k_zero<<<(N_NODES + 255) / 256, 256, 0, stream>>>(counts);
    k_count<<<(N_EDGESN + 255) / 256, 256, 0, stream>>>(col, counts);
    k_scan<<<1, 1024, 0, stream>>>(counts, offs, cursor, dis);
    k_scatter<<<(E_TOT + 255) / 256, 256, 0, stream>>>(row, col, dis, cursor, csr);
    k_lin1<<<N_NODES / 2, 256, 0, stream>>>(x, lin1_w, lin1_b, x_all);

    const int attn_blocks = (N_NODES + 3) / 4;
    for (int l = 0; l < LLAYERS; l++) {
        switch (l) {
            case 0: k_attn_fly<1><<<attn_blocks, 256, 0, stream>>>(offs, csr, dis, Wq, bq, Wk, bk, Wv, bv, x_all); break;
            case 1: k_attn_fly<2><<<attn_blocks, 256, 0, stream>>>(offs, csr, dis, Wq, bq, Wk, bk, Wv, bv, x_all); break;
            case 2: k_attn_fly<3><<<attn_blocks, 256, 0, stream>>>(offs, csr, dis, Wq, bq, Wk, bk, Wv, bv, x_all); break;
            case 3: k_attn_fly<4><<<attn_blocks, 256, 0, stream>>>(offs, csr, dis, Wq, bq, Wk, bk, Wv, bv, x_all); break;
            case 4: k_attn_fly<5><<<attn_blocks, 256, 0, stream>>>(offs, csr, dis, Wq, bq, Wk, bk, Wv, bv, x_all); break;
        }
    }
    k_lin2<<<(N_NODES + 15) / 16, 256, 0, stream>>>(x_all, lin2_w, lin2_b, outp);
}